// Round 16
// baseline (420.764 us; speedup 1.0000x reference)
//
#include <hip/hip_runtime.h>
#include <hip/hip_bf16.h>

#define NREL 3
#define EMB 32
#define HID 64
#define OVCAP 1024   // l1 in-LDS overflow list capacity
#define OVDUMP 63    // overflow entries dumped for l2 (P(block ovf > 63) ~ e^-38)
#define BCAP 1024    // per-bucket pk capacity (words); bucket Poisson(~320)

typedef __attribute__((ext_vector_type(8))) short short8_t;
typedef __attribute__((ext_vector_type(4))) short short4_t;
typedef __attribute__((ext_vector_type(4))) float f32x4;

__device__ inline short f2bf(float v) {
  __hip_bfloat16 b = __float2bfloat16(v);
  short s;
  __builtin_memcpy(&s, &b, 2);
  return s;
}
__device__ inline float bf2f(short s) {
  __hip_bfloat16 b;
  __builtin_memcpy(&b, &s, 2);
  return __bfloat162float(b);
}
__device__ inline void split8(const float* v, short8_t* h, short8_t* l) {
#pragma unroll
  for (int i = 0; i < 8; i++) {
    short hh = f2bf(v[i]);
    (*h)[i] = hh;
    (*l)[i] = f2bf(v[i] - bf2f(hh));
  }
}

// ---- fused prep: embedding (hi/lo) + DIRECT bucket append + weight prep ----
__global__ __launch_bounds__(256) void prep_k(
    const int* __restrict__ sid, const int* __restrict__ cid, const int* __restrict__ pid,
    const float* __restrict__ se, const float* __restrict__ ce, const float* __restrict__ pe,
    short* __restrict__ xh, short* __restrict__ xl,
    const int* __restrict__ src, const int* __restrict__ dst, const int* __restrict__ et,
    int* __restrict__ bcur, unsigned* __restrict__ pk,
    const float* __restrict__ root1, const float* __restrict__ W1,
    const float* __restrict__ root2, const float* __restrict__ W2,
    short* __restrict__ w1h, short* __restrict__ w1l,
    short* __restrict__ w2h, short* __restrict__ w2l, int N, int E) {
  int i = blockIdx.x * 256 + threadIdx.x;
  if (i < N * 8) {  // embedding: one float4 slice per thread
    int n = i >> 3, cg = i & 7;
    const float4 a = *(const float4*)&se[sid[n] * EMB + cg * 4];
    const float4 b = *(const float4*)&ce[cid[n] * EMB + cg * 4];
    const float4 c = *(const float4*)&pe[pid[n] * EMB + cg * 4];
    float v[4];
    v[0] = a.x + b.x + c.x; v[1] = a.y + b.y + c.y;
    v[2] = a.z + b.z + c.z; v[3] = a.w + b.w + c.w;
    short4_t h, l;
#pragma unroll
    for (int j = 0; j < 4; j++) {
      short hh = f2bf(v[j]);
      h[j] = hh;
      l[j] = f2bf(v[j] - bf2f(hh));
    }
    *(short4_t*)&xh[(size_t)n * EMB + cg * 4] = h;
    *(short4_t*)&xl[(size_t)n * EMB + cg * 4] = l;
  }
  if (i < E) {  // direct bucket append: histogram atomic IS the append atomic
    int d = dst[i];
    int b = d >> 6;
    int j = atomicAdd(&bcur[b * 16], 1);  // one counter per 64B line
    if (j < BCAP)
      pk[(size_t)b * BCAP + j] =
          ((unsigned)(d & 63) << 21) | ((unsigned)et[i] << 19) | (unsigned)src[i];
  }
  if (i < 64 * 128) {  // layer-1 weights
    int k = i >> 6, n = i & 63;
    float v = (k < EMB) ? root1[k * 64 + n] : W1[(k - EMB) * 64 + n];
    short h = f2bf(v);
    w1h[n * 128 + k] = h;
    w1l[n * 128 + k] = f2bf(v - bf2f(h));
  }
  if (i < 64 * 256) {  // layer-2 weights
    int k = i >> 6, n = i & 63;
    float v = (k < HID) ? root2[k * 64 + n] : W2[(k - HID) * 64 + n];
    short h = f2bf(v);
    w2h[n * 256 + k] = h;
    w2l[n * 256 + k] = f2bf(v - bf2f(h));
  }
}

// ====== layer-1: in-LDS CSR build (+dump for l2) + register gather + phased MFMA ======
// After the build, the finished CSR (mid/cnt/ovn/ovf) is dumped into this block's OWN
// pk segment (already fully consumed) so l2 can skip the build entirely.
// Segment layout (words): [0,768)=mid int4s, [768,960)=cnt, [960]=ovn, [961,1024)=ovf.
__global__ __launch_bounds__(256) void l1fused_k(
    const short* __restrict__ xh, const short* __restrict__ xl,
    const int* __restrict__ bcur, unsigned* __restrict__ pk,
    const short* __restrict__ wth, const short* __restrict__ wtl,
    const float* __restrict__ bias, short* __restrict__ h1h, short* __restrict__ h1l, int N) {
  __shared__ __align__(16) short lws[64][16][8];  // 16 KB (one plane)
  __shared__ __align__(16) int4 mid_s[192];       //  3 KB (first-4 ids)
  __shared__ int cnt_s[192];
  __shared__ unsigned ovf_s[OVCAP];               //  4 KB (slot<<19 | src)
  __shared__ int ovfn_s;

  const int t = threadIdx.x;
  const int lane = t & 63, w = t >> 6;
  const int m_ = lane & 15, q = lane >> 4;
  const int n0b = blockIdx.x * 64;

  // ---- phase A: hi-plane weights -> LDS, self -> regs, init build state ----
  int node_c = n0b + w * 16 + m_;
  if (node_c >= N) node_c = N - 1;
  short8_t ah0 = *(const short8_t*)&xh[(size_t)node_c * EMB + q * 8];
  short8_t al0 = *(const short8_t*)&xl[(size_t)node_c * EMB + q * 8];
#pragma unroll
  for (int i = 0; i < 4; i++) {
    int chi = t + 256 * i;
    int row = chi >> 4, c = chi & 15;
    short8_t wv = *(const short8_t*)&wth[(size_t)row * 128 + c * 8];
    *(short8_t*)&lws[row][c ^ (row & 7)][0] = wv;
  }
  if (t < 192) cnt_s[t] = 0;
  if (t == 0) ovfn_s = 0;
  __syncthreads();

  // ---- phase B: in-LDS CSR build (1 LDS atomic/edge) ----
  {
    int ne = bcur[blockIdx.x * 16];
    if (ne > BCAP) ne = BCAP;
    const size_t base = (size_t)blockIdx.x * BCAP;
    for (int e = t; e < ne; e += 256) {
      unsigned p = pk[base + e];
      int srcn = (int)(p & 0x7FFFF);
      int slot = (int)((p >> 19) & 3) * 64 + (int)(p >> 21);
      int j = atomicAdd(&cnt_s[slot], 1);
      if (j < 4) ((int*)&mid_s[slot])[j] = srcn;
      else {
        int k2 = atomicAdd(&ovfn_s, 1);
        if (k2 < OVCAP) ovf_s[k2] = ((unsigned)slot << 19) | (unsigned)srcn;
      }
    }
  }
  __syncthreads();

  // ---- dump finished CSR into our own (consumed) pk segment for l2 ----
  {
    unsigned* seg = &pk[(size_t)blockIdx.x * BCAP];
    if (t < 192) {
      *(int4*)&seg[t * 4] = mid_s[t];
      seg[768 + t] = (unsigned)cnt_s[t];
    }
    int ovn = ovfn_s;
    if (ovn > OVDUMP) ovn = OVDUMP;
    if (t == 0) seg[960] = (unsigned)ovn;
    for (int i = t; i < ovn; i += 256) seg[961 + i] = ovf_s[i];
  }

  // ---- phase S': consumer-aligned gather -> REGISTER fragments ----
  short8_t ahv[4], alv[4];
  ahv[0] = ah0;
  alv[0] = al0;
  {
    int ovn = ovfn_s;
    if (ovn > OVCAP) ovn = OVCAP;
    int tslot[3], tlen[3];
    int4 tid4[3];
#pragma unroll
    for (int k = 0; k < 3; k++) {
      tslot[k] = k * 64 + w * 16 + m_;  // the slots THIS thread consumes (g=k+1)
      tid4[k] = mid_s[tslot[k]];
      tlen[k] = cnt_s[tslot[k]];
    }
    short8_t v0[3], v1[3], v2[3], v3[3];
#pragma unroll
    for (int k = 0; k < 3; k++) {
      int nself = n0b + (tslot[k] & 63);
      if (nself >= N) nself = N - 1;
      int g0 = (0 < tlen[k]) ? tid4[k].x : nself;
      int g1 = (1 < tlen[k]) ? tid4[k].y : nself;
      int g2 = (2 < tlen[k]) ? tid4[k].z : nself;
      int g3 = (3 < tlen[k]) ? tid4[k].w : nself;
      size_t co = (size_t)q * 8;
      v0[k] = *(const short8_t*)&xh[(size_t)g0 * EMB + co];
      v1[k] = *(const short8_t*)&xh[(size_t)g1 * EMB + co];
      v2[k] = *(const short8_t*)&xh[(size_t)g2 * EMB + co];
      v3[k] = *(const short8_t*)&xh[(size_t)g3 * EMB + co];
    }
#pragma unroll
    for (int k = 0; k < 3; k++) {
      float a[8];
      float k0 = (0 < tlen[k]) ? 1.f : 0.f;
      float k1 = (1 < tlen[k]) ? 1.f : 0.f;
      float k2 = (2 < tlen[k]) ? 1.f : 0.f;
      float k3 = (3 < tlen[k]) ? 1.f : 0.f;
#pragma unroll
      for (int i = 0; i < 8; i++)
        a[i] = k0 * bf2f(v0[k][i]) + k1 * bf2f(v1[k][i]) + k2 * bf2f(v2[k][i]) +
               k3 * bf2f(v3[k][i]);
      // rare tail: scan tiny LDS overflow list (~6 entries/bucket)
      for (int k3_ = 0; k3_ < ovn; k3_++) {
        unsigned ov = ovf_s[k3_];
        if ((int)(ov >> 19) == tslot[k]) {
          short8_t u = *(const short8_t*)&xh[(size_t)(ov & 0x7FFFF) * EMB + q * 8];
#pragma unroll
          for (int i = 0; i < 8; i++) a[i] += bf2f(u[i]);
        }
      }
      float inv = 1.f / fmaxf((float)tlen[k], 1.f);
#pragma unroll
      for (int i = 0; i < 8; i++) a[i] *= inv;
      split8(a, &ahv[k + 1], &alv[k + 1]);
    }
  }

  // ---- phase Ca: hi-plane MFMAs ----
  f32x4 acc[4];
#pragma unroll
  for (int i = 0; i < 4; i++) acc[i] = (f32x4){0.f, 0.f, 0.f, 0.f};
#pragma unroll
  for (int g = 0; g < 4; g++) {
#pragma unroll
    for (int tt = 0; tt < 4; tt++) {
      int row = 16 * tt + m_;
      int cs = (g * 4 + q) ^ (row & 7);
      short8_t bh = *(const short8_t*)&lws[row][cs][0];
      acc[tt] = __builtin_amdgcn_mfma_f32_16x16x32_bf16(ahv[g], bh, acc[tt], 0, 0, 0);
      acc[tt] = __builtin_amdgcn_mfma_f32_16x16x32_bf16(alv[g], bh, acc[tt], 0, 0, 0);
    }
  }
  __syncthreads();

  // ---- phase St: stage lo-plane weights ----
#pragma unroll
  for (int i = 0; i < 4; i++) {
    int chi = t + 256 * i;
    int row = chi >> 4, c = chi & 15;
    short8_t wv = *(const short8_t*)&wtl[(size_t)row * 128 + c * 8];
    *(short8_t*)&lws[row][c ^ (row & 7)][0] = wv;
  }
  __syncthreads();

  // ---- phase Cb: lo-plane MFMAs ----
#pragma unroll
  for (int g = 0; g < 4; g++) {
#pragma unroll
    for (int tt = 0; tt < 4; tt++) {
      int row = 16 * tt + m_;
      int cs = (g * 4 + q) ^ (row & 7);
      short8_t bl = *(const short8_t*)&lws[row][cs][0];
      acc[tt] = __builtin_amdgcn_mfma_f32_16x16x32_bf16(ahv[g], bl, acc[tt], 0, 0, 0);
    }
  }
  // epilogue: bias + relu + hi/lo split store
#pragma unroll
  for (int tt = 0; tt < 4; tt++) {
    float bia = bias[16 * tt + m_];
#pragma unroll
    for (int reg = 0; reg < 4; reg++) {
      int node = n0b + w * 16 + q * 4 + reg;
      if (node < N) {
        float val = fmaxf(acc[tt][reg] + bia, 0.f);
        short hh = f2bf(val);
        h1h[(size_t)node * HID + 16 * tt + m_] = hh;
        h1l[(size_t)node * HID + 16 * tt + m_] = f2bf(val - bf2f(hh));
      }
    }
  }
}

// ====== layer-2: pre-built CSR from pk segment + merged register gather + phased MFMA ======
__global__ __launch_bounds__(256) void l2fused_k(
    const short* __restrict__ h1h, const short* __restrict__ h1l,
    const unsigned* __restrict__ pk,
    const short* __restrict__ wth, const short* __restrict__ wtl,
    const float* __restrict__ bias, const float* __restrict__ linW,
    const int* __restrict__ batch, float* __restrict__ gs, float* __restrict__ gc, int N) {
  __shared__ __align__(16) short lws[64][16][8];  // 16 KB (one plane, one K-half)
  __shared__ unsigned ovf_s[OVDUMP + 1];          // 256 B

  const int t = threadIdx.x;
  const int lane = t & 63, w = t >> 6;
  const int m_ = lane & 15, q = lane >> 4;
  const int n0b = blockIdx.x * 64;
  const unsigned* seg = &pk[(size_t)blockIdx.x * BCAP];

  // ---- phase A: hi-weights(s0) -> LDS; stage overflow list ----
  int node_c = n0b + w * 16 + m_;
  if (node_c >= N) node_c = N - 1;
#pragma unroll
  for (int i = 0; i < 4; i++) {
    int chi = t + 256 * i;
    int row = chi >> 4, c = chi & 15;
    int g = c >> 2, qq = c & 3;
    short8_t wv = *(const short8_t*)&wth[(size_t)row * 256 + g * 64 + 0 * 32 + qq * 8];
    *(short8_t*)&lws[row][c ^ (row & 7)][0] = wv;
  }
  int ovn = (int)seg[960];
  if (ovn > OVDUMP) ovn = OVDUMP;
  for (int i = t; i < ovn; i += 256) ovf_s[i] = seg[961 + i];
  __syncthreads();

  // ---- phase S'': merged both-K-half consumer-aligned gather -> register fragments ----
  short8_t ahv0[4], alv0[4], ahv1[4], alv1[4];
  {
    ahv0[0] = *(const short8_t*)&h1h[(size_t)node_c * HID + q * 8];
    alv0[0] = *(const short8_t*)&h1l[(size_t)node_c * HID + q * 8];
    ahv1[0] = *(const short8_t*)&h1h[(size_t)node_c * HID + 32 + q * 8];
    alv1[0] = *(const short8_t*)&h1l[(size_t)node_c * HID + 32 + q * 8];
    int tslot[3], tlen[3];
    int4 tid4[3];
    int gid[3][4];
#pragma unroll
    for (int k = 0; k < 3; k++) {
      tslot[k] = k * 64 + w * 16 + m_;
      tid4[k] = *(const int4*)&seg[tslot[k] * 4];
      tlen[k] = (int)seg[768 + tslot[k]];
      int nself = n0b + (tslot[k] & 63);
      if (nself >= N) nself = N - 1;
      gid[k][0] = (0 < tlen[k]) ? tid4[k].x : nself;
      gid[k][1] = (1 < tlen[k]) ? tid4[k].y : nself;
      gid[k][2] = (2 < tlen[k]) ? tid4[k].z : nself;
      gid[k][3] = (3 < tlen[k]) ? tid4[k].w : nself;
    }
    float a0[3][8], a1[3][8];
    // batch half-0
    {
      short8_t v0[3], v1[3], v2[3], v3[3];
#pragma unroll
      for (int k = 0; k < 3; k++) {
        size_t co = (size_t)q * 8;
        v0[k] = *(const short8_t*)&h1h[(size_t)gid[k][0] * HID + co];
        v1[k] = *(const short8_t*)&h1h[(size_t)gid[k][1] * HID + co];
        v2[k] = *(const short8_t*)&h1h[(size_t)gid[k][2] * HID + co];
        v3[k] = *(const short8_t*)&h1h[(size_t)gid[k][3] * HID + co];
      }
#pragma unroll
      for (int k = 0; k < 3; k++) {
        float k0 = (0 < tlen[k]) ? 1.f : 0.f;
        float k1 = (1 < tlen[k]) ? 1.f : 0.f;
        float k2 = (2 < tlen[k]) ? 1.f : 0.f;
        float k3 = (3 < tlen[k]) ? 1.f : 0.f;
#pragma unroll
        for (int i = 0; i < 8; i++)
          a0[k][i] = k0 * bf2f(v0[k][i]) + k1 * bf2f(v1[k][i]) + k2 * bf2f(v2[k][i]) +
                     k3 * bf2f(v3[k][i]);
      }
    }
    // batch half-1: same rows +64B (L1-resident)
    {
      short8_t v0[3], v1[3], v2[3], v3[3];
#pragma unroll
      for (int k = 0; k < 3; k++) {
        size_t co = 32 + (size_t)q * 8;
        v0[k] = *(const short8_t*)&h1h[(size_t)gid[k][0] * HID + co];
        v1[k] = *(const short8_t*)&h1h[(size_t)gid[k][1] * HID + co];
        v2[k] = *(const short8_t*)&h1h[(size_t)gid[k][2] * HID + co];
        v3[k] = *(const short8_t*)&h1h[(size_t)gid[k][3] * HID + co];
      }
#pragma unroll
      for (int k = 0; k < 3; k++) {
        float k0 = (0 < tlen[k]) ? 1.f : 0.f;
        float k1 = (1 < tlen[k]) ? 1.f : 0.f;
        float k2 = (2 < tlen[k]) ? 1.f : 0.f;
        float k3 = (3 < tlen[k]) ? 1.f : 0.f;
#pragma unroll
        for (int i = 0; i < 8; i++)
          a1[k][i] = k0 * bf2f(v0[k][i]) + k1 * bf2f(v1[k][i]) + k2 * bf2f(v2[k][i]) +
                     k3 * bf2f(v3[k][i]);
      }
    }
    // rare tail: overflow entries contribute to both halves
#pragma unroll
    for (int k = 0; k < 3; k++) {
      for (int k3_ = 0; k3_ < ovn; k3_++) {
        unsigned ov = ovf_s[k3_];
        if ((int)(ov >> 19) == tslot[k]) {
          const short* p = &h1h[(size_t)(ov & 0x7FFFF) * HID];
          short8_t u0 = *(const short8_t*)&p[q * 8];
          short8_t u1 = *(const short8_t*)&p[32 + q * 8];
#pragma unroll
          for (int i = 0; i < 8; i++) {
            a0[k][i] += bf2f(u0[i]);
            a1[k][i] += bf2f(u1[i]);
          }
        }
      }
      float inv = 1.f / fmaxf((float)tlen[k], 1.f);
#pragma unroll
      for (int i = 0; i < 8; i++) {
        a0[k][i] *= inv;
        a1[k][i] *= inv;
      }
      split8(a0[k], &ahv0[k + 1], &alv0[k + 1]);
      split8(a1[k], &ahv1[k + 1], &alv1[k + 1]);
    }
  }

  // ---- weight-phase sequence: 4 stages x MFMA, fragments from registers ----
  f32x4 acc[4];
#pragma unroll
  for (int i = 0; i < 4; i++) acc[i] = (f32x4){0.f, 0.f, 0.f, 0.f};
#pragma unroll
  for (int s_ = 0; s_ < 2; s_++) {
    if (s_ == 1) {  // re-stage hi-weights for K-half 1
#pragma unroll
      for (int i = 0; i < 4; i++) {
        int chi = t + 256 * i;
        int row = chi >> 4, c = chi & 15;
        int g = c >> 2, q2 = c & 3;
        short8_t wv = *(const short8_t*)&wth[(size_t)row * 256 + g * 64 + 32 + q2 * 8];
        *(short8_t*)&lws[row][c ^ (row & 7)][0] = wv;
      }
      __syncthreads();
    }
    // Ca(s_): hi-plane MFMAs
#pragma unroll
    for (int g = 0; g < 4; g++) {
      short8_t ah = (s_ == 0) ? ahv0[g] : ahv1[g];
      short8_t al = (s_ == 0) ? alv0[g] : alv1[g];
#pragma unroll
      for (int tt = 0; tt < 4; tt++) {
        int row = 16 * tt + m_;
        int cs = (g * 4 + q) ^ (row & 7);
        short8_t bh = *(const short8_t*)&lws[row][cs][0];
        acc[tt] = __builtin_amdgcn_mfma_f32_16x16x32_bf16(ah, bh, acc[tt], 0, 0, 0);
        acc[tt] = __builtin_amdgcn_mfma_f32_16x16x32_bf16(al, bh, acc[tt], 0, 0, 0);
      }
    }
    __syncthreads();
    // St(s_): stage lo-plane weights for this K-half
#pragma unroll
    for (int i = 0; i < 4; i++) {
      int chi = t + 256 * i;
      int row = chi >> 4, c = chi & 15;
      int g = c >> 2, q2 = c & 3;
      short8_t wv = *(const short8_t*)&wtl[(size_t)row * 256 + g * 64 + s_ * 32 + q2 * 8];
      *(short8_t*)&lws[row][c ^ (row & 7)][0] = wv;
    }
    __syncthreads();
    // Cb(s_): lo-plane MFMAs
#pragma unroll
    for (int g = 0; g < 4; g++) {
      short8_t ah = (s_ == 0) ? ahv0[g] : ahv1[g];
#pragma unroll
      for (int tt = 0; tt < 4; tt++) {
        int row = 16 * tt + m_;
        int cs = (g * 4 + q) ^ (row & 7);
        short8_t bl = *(const short8_t*)&lws[row][cs][0];
        acc[tt] = __builtin_amdgcn_mfma_f32_16x16x32_bf16(ah, bl, acc[tt], 0, 0, 0);
      }
    }
    if (s_ == 0) __syncthreads();  // protect lws before next hi-stage
  }

  // ---- pooled epilogue ----
  float bia[4], lw0[4], lw1[4];
#pragma unroll
  for (int tt = 0; tt < 4; tt++) {
    int col = 16 * tt + m_;
    bia[tt] = bias[col];
    lw0[tt] = linW[col * 2 + 0];
    lw1[tt] = linW[col * 2 + 1];
  }
#pragma unroll
  for (int reg = 0; reg < 4; reg++) {
    int node = n0b + w * 16 + q * 4 + reg;
    float p0 = 0.f, p1 = 0.f;
#pragma unroll
    for (int tt = 0; tt < 4; tt++) {
      float v = fmaxf(acc[tt][reg] + bia[tt], 0.f);
      p0 += v * lw0[tt];
      p1 += v * lw1[tt];
    }
#pragma unroll
    for (int o = 1; o < 16; o <<= 1) {
      p0 += __shfl_xor(p0, o, 64);
      p1 += __shfl_xor(p1, o, 64);
    }
    if (m_ == 0 && node < N) {
      int g = batch[node];
      atomicAdd(&gs[g * 2 + 0], p0);
      atomicAdd(&gs[g * 2 + 1], p1);
      atomicAdd(&gc[g], 1.0f);
    }
  }
}

__global__ __launch_bounds__(256) void final_k(const float* __restrict__ gs,
                                               const float* __restrict__ gc,
                                               const float* __restrict__ linb,
                                               float* __restrict__ out, int G) {
  int i = blockIdx.x * 256 + threadIdx.x;
  if (i >= G * 2) return;
  int g = i >> 1, o = i & 1;
  out[i] = gs[i] / fmaxf(gc[g], 1.0f) + linb[o];
}

extern "C" void kernel_launch(void* const* d_in, const int* in_sizes, int n_in,
                              void* d_out, int out_size, void* d_ws, size_t ws_size,
                              hipStream_t stream) {
  const int* sid = (const int*)d_in[0];
  const int* cid = (const int*)d_in[1];
  const int* pid = (const int*)d_in[2];
  const int* ei = (const int*)d_in[3];
  const int* et = (const int*)d_in[4];
  const int* batch = (const int*)d_in[5];
  const float* se = (const float*)d_in[7];
  const float* ce = (const float*)d_in[8];
  const float* pe = (const float*)d_in[9];
  const float* W1 = (const float*)d_in[10];
  const float* root1 = (const float*)d_in[11];
  const float* b1 = (const float*)d_in[12];
  const float* W2 = (const float*)d_in[13];
  const float* root2 = (const float*)d_in[14];
  const float* b2 = (const float*)d_in[15];
  const float* linW = (const float*)d_in[16];
  const float* linb = (const float*)d_in[17];
  float* out = (float*)d_out;

  const int N = in_sizes[0];
  const int E = in_sizes[4];
  const int G = out_size / 2;
  const int* src = ei;
  const int* dst = ei + E;
  const int NBk = (N + 63) / 64;     // buckets == fused-layer blocks
  const int NBa = (NBk + 15) & ~15;  // aligned allocation

  // ---- workspace layout (16B-aligned; bcur|gs|gc adjacent for one memset) ----
  char* w = (char*)d_ws;
  short* h1h = (short*)w;  w += (size_t)N * HID * sizeof(short);
  short* h1l = (short*)w;  w += (size_t)N * HID * sizeof(short);
  short* xh = (short*)w;   w += (size_t)N * EMB * sizeof(short);
  short* xl = (short*)w;   w += (size_t)N * EMB * sizeof(short);
  int* bcur = (int*)w;     w += (size_t)NBa * 16 * sizeof(int);  // 64B-padded cursors
  float* gs = (float*)w;   w += (size_t)G * 2 * sizeof(float);
  float* gc = (float*)w;   w += (size_t)G * sizeof(float);
  unsigned* pk = (unsigned*)w; w += (size_t)NBa * BCAP * sizeof(unsigned);  // 19.2 MB
  short* w1h = (short*)w;  w += (size_t)64 * 128 * sizeof(short);
  short* w1l = (short*)w;  w += (size_t)64 * 128 * sizeof(short);
  short* w2h = (short*)w;  w += (size_t)64 * 256 * sizeof(short);
  short* w2l = (short*)w;  w += (size_t)64 * 256 * sizeof(short);
  if ((size_t)(w - (char*)d_ws) > ws_size) return;  // fail loudly, no OOB

  // single memset covers bcur + gs + gc (adjacent)
  hipMemsetAsync(bcur, 0, (size_t)NBa * 16 * sizeof(int) + (size_t)G * 3 * sizeof(float),
                 stream);

  int prep_n = N * 8;  // covers E (1.5M) and weight ranges too for this problem size
  if (prep_n < E) prep_n = E;
  if (prep_n < 64 * 256) prep_n = 64 * 256;
  prep_k<<<(prep_n + 255) / 256, 256, 0, stream>>>(sid, cid, pid, se, ce, pe, xh, xl, src,
                                                   dst, et, bcur, pk, root1, W1, root2, W2,
                                                   w1h, w1l, w2h, w2l, N, E);

  l1fused_k<<<NBk, 256, 0, stream>>>(xh, xl, bcur, pk, w1h, w1l, b1, h1h, h1l, N);
  l2fused_k<<<NBk, 256, 0, stream>>>(h1h, h1l, pk, w2h, w2l, b2, linW, batch, gs, gc, N);
  final_k<<<(G * 2 + 255) / 256, 256, 0, stream>>>(gs, gc, linb, out, G);
}

// Round 17
// 400.757 us; speedup vs baseline: 1.0499x; 1.0499x over previous
//
#include <hip/hip_runtime.h>
#include <hip/hip_bf16.h>

#define NREL 3
#define EMB 32
#define HID 64
#define OVCAP 1024
#define BCAP 1024  // per-bucket pk capacity; buckets Poisson(~320), P(>1024)~e^-487

typedef __attribute__((ext_vector_type(8))) short short8_t;
typedef __attribute__((ext_vector_type(4))) short short4_t;
typedef __attribute__((ext_vector_type(4))) float f32x4;

__device__ inline short f2bf(float v) {
  __hip_bfloat16 b = __float2bfloat16(v);
  short s;
  __builtin_memcpy(&s, &b, 2);
  return s;
}
__device__ inline float bf2f(short s) {
  __hip_bfloat16 b;
  __builtin_memcpy(&b, &s, 2);
  return __bfloat162float(b);
}
__device__ inline void split8(const float* v, short8_t* h, short8_t* l) {
#pragma unroll
  for (int i = 0; i < 8; i++) {
    short hh = f2bf(v[i]);
    (*h)[i] = hh;
    (*l)[i] = f2bf(v[i] - bf2f(hh));
  }
}

// ---- fused prep: embedding (hi/lo) + DIRECT bucket append + weight prep ----
__global__ __launch_bounds__(256) void prep_k(
    const int* __restrict__ sid, const int* __restrict__ cid, const int* __restrict__ pid,
    const float* __restrict__ se, const float* __restrict__ ce, const float* __restrict__ pe,
    short* __restrict__ xh, short* __restrict__ xl,
    const int* __restrict__ src, const int* __restrict__ dst, const int* __restrict__ et,
    int* __restrict__ bcur, unsigned* __restrict__ pk,
    const float* __restrict__ root1, const float* __restrict__ W1,
    const float* __restrict__ root2, const float* __restrict__ W2,
    short* __restrict__ w1h, short* __restrict__ w1l,
    short* __restrict__ w2h, short* __restrict__ w2l, int N, int E) {
  int i = blockIdx.x * 256 + threadIdx.x;
  if (i < N * 8) {  // embedding: one float4 slice per thread
    int n = i >> 3, cg = i & 7;
    const float4 a = *(const float4*)&se[sid[n] * EMB + cg * 4];
    const float4 b = *(const float4*)&ce[cid[n] * EMB + cg * 4];
    const float4 c = *(const float4*)&pe[pid[n] * EMB + cg * 4];
    float v[4];
    v[0] = a.x + b.x + c.x; v[1] = a.y + b.y + c.y;
    v[2] = a.z + b.z + c.z; v[3] = a.w + b.w + c.w;
    short4_t h, l;
#pragma unroll
    for (int j = 0; j < 4; j++) {
      short hh = f2bf(v[j]);
      h[j] = hh;
      l[j] = f2bf(v[j] - bf2f(hh));
    }
    *(short4_t*)&xh[(size_t)n * EMB + cg * 4] = h;
    *(short4_t*)&xl[(size_t)n * EMB + cg * 4] = l;
  }
  if (i < E) {  // direct bucket append: histogram atomic IS the append atomic
    int d = dst[i];
    int b = d >> 6;
    int j = atomicAdd(&bcur[b * 16], 1);  // one counter per 64B line
    if (j < BCAP)
      pk[(size_t)b * BCAP + j] =
          ((unsigned)(d & 63) << 21) | ((unsigned)et[i] << 19) | (unsigned)src[i];
  }
  if (i < 64 * 128) {  // layer-1 weights
    int k = i >> 6, n = i & 63;
    float v = (k < EMB) ? root1[k * 64 + n] : W1[(k - EMB) * 64 + n];
    short h = f2bf(v);
    w1h[n * 128 + k] = h;
    w1l[n * 128 + k] = f2bf(v - bf2f(h));
  }
  if (i < 64 * 256) {  // layer-2 weights
    int k = i >> 6, n = i & 63;
    float v = (k < HID) ? root2[k * 64 + n] : W2[(k - HID) * 64 + n];
    short h = f2bf(v);
    w2h[n * 256 + k] = h;
    w2l[n * 256 + k] = f2bf(v - bf2f(h));
  }
}

// ====== layer-1: in-LDS CSR build + consumer-aligned register gather + phased MFMA ======
__global__ __launch_bounds__(256) void l1fused_k(
    const short* __restrict__ xh, const short* __restrict__ xl,
    const int* __restrict__ bcur, const unsigned* __restrict__ pk,
    const short* __restrict__ wth, const short* __restrict__ wtl,
    const float* __restrict__ bias, short* __restrict__ h1h, short* __restrict__ h1l, int N) {
  __shared__ __align__(16) short lws[64][16][8];  // 16 KB (one plane)
  __shared__ __align__(16) int4 mid_s[192];       //  3 KB (first-4 ids)
  __shared__ int cnt_s[192];
  __shared__ unsigned ovf_s[OVCAP];               //  4 KB (slot<<19 | src)
  __shared__ int ovfn_s;

  const int t = threadIdx.x;
  const int lane = t & 63, w = t >> 6;
  const int m_ = lane & 15, q = lane >> 4;
  const int n0b = blockIdx.x * 64;

  // ---- phase A: hi-plane weights -> LDS, self -> regs, init build state ----
  int node_c = n0b + w * 16 + m_;
  if (node_c >= N) node_c = N - 1;
  short8_t ah0 = *(const short8_t*)&xh[(size_t)node_c * EMB + q * 8];
  short8_t al0 = *(const short8_t*)&xl[(size_t)node_c * EMB + q * 8];
#pragma unroll
  for (int i = 0; i < 4; i++) {
    int chi = t + 256 * i;
    int row = chi >> 4, c = chi & 15;
    short8_t wv = *(const short8_t*)&wth[(size_t)row * 128 + c * 8];
    *(short8_t*)&lws[row][c ^ (row & 7)][0] = wv;
  }
  if (t < 192) cnt_s[t] = 0;
  if (t == 0) ovfn_s = 0;
  __syncthreads();

  // ---- phase B: in-LDS CSR build (1 LDS atomic/edge) ----
  {
    int ne = bcur[blockIdx.x * 16];
    if (ne > BCAP) ne = BCAP;
    const size_t base = (size_t)blockIdx.x * BCAP;
    for (int e = t; e < ne; e += 256) {
      unsigned p = pk[base + e];
      int srcn = (int)(p & 0x7FFFF);
      int slot = (int)((p >> 19) & 3) * 64 + (int)(p >> 21);
      int j = atomicAdd(&cnt_s[slot], 1);
      if (j < 4) ((int*)&mid_s[slot])[j] = srcn;
      else {
        int k2 = atomicAdd(&ovfn_s, 1);
        if (k2 < OVCAP) ovf_s[k2] = ((unsigned)slot << 19) | (unsigned)srcn;
      }
    }
  }
  __syncthreads();

  // ---- phase S': consumer-aligned gather -> REGISTER fragments (no LDS round-trip) ----
  short8_t ahv[4], alv[4];
  ahv[0] = ah0;
  alv[0] = al0;
  {
    int ovn = ovfn_s;
    if (ovn > OVCAP) ovn = OVCAP;
    int tslot[3], tlen[3];
    int4 tid4[3];
#pragma unroll
    for (int k = 0; k < 3; k++) {
      tslot[k] = k * 64 + w * 16 + m_;  // the slots THIS thread consumes (g=k+1)
      tid4[k] = mid_s[tslot[k]];
      tlen[k] = cnt_s[tslot[k]];
    }
    short8_t v0[3], v1[3], v2[3], v3[3];
#pragma unroll
    for (int k = 0; k < 3; k++) {
      int nself = n0b + (tslot[k] & 63);
      if (nself >= N) nself = N - 1;
      int g0 = (0 < tlen[k]) ? tid4[k].x : nself;
      int g1 = (1 < tlen[k]) ? tid4[k].y : nself;
      int g2 = (2 < tlen[k]) ? tid4[k].z : nself;
      int g3 = (3 < tlen[k]) ? tid4[k].w : nself;
      size_t co = (size_t)q * 8;
      v0[k] = *(const short8_t*)&xh[(size_t)g0 * EMB + co];
      v1[k] = *(const short8_t*)&xh[(size_t)g1 * EMB + co];
      v2[k] = *(const short8_t*)&xh[(size_t)g2 * EMB + co];
      v3[k] = *(const short8_t*)&xh[(size_t)g3 * EMB + co];
    }
#pragma unroll
    for (int k = 0; k < 3; k++) {
      float a[8];
      float k0 = (0 < tlen[k]) ? 1.f : 0.f;
      float k1 = (1 < tlen[k]) ? 1.f : 0.f;
      float k2 = (2 < tlen[k]) ? 1.f : 0.f;
      float k3 = (3 < tlen[k]) ? 1.f : 0.f;
#pragma unroll
      for (int i = 0; i < 8; i++)
        a[i] = k0 * bf2f(v0[k][i]) + k1 * bf2f(v1[k][i]) + k2 * bf2f(v2[k][i]) +
               k3 * bf2f(v3[k][i]);
      // rare tail: scan tiny LDS overflow list (~6 entries/bucket)
      for (int k3_ = 0; k3_ < ovn; k3_++) {
        unsigned ov = ovf_s[k3_];
        if ((int)(ov >> 19) == tslot[k]) {
          short8_t u = *(const short8_t*)&xh[(size_t)(ov & 0x7FFFF) * EMB + q * 8];
#pragma unroll
          for (int i = 0; i < 8; i++) a[i] += bf2f(u[i]);
        }
      }
      float inv = 1.f / fmaxf((float)tlen[k], 1.f);
#pragma unroll
      for (int i = 0; i < 8; i++) a[i] *= inv;
      split8(a, &ahv[k + 1], &alv[k + 1]);
    }
  }

  // ---- phase Ca: hi-plane MFMAs (lws stable since phase A; no barrier needed) ----
  f32x4 acc[4];
#pragma unroll
  for (int i = 0; i < 4; i++) acc[i] = (f32x4){0.f, 0.f, 0.f, 0.f};
#pragma unroll
  for (int g = 0; g < 4; g++) {
#pragma unroll
    for (int tt = 0; tt < 4; tt++) {
      int row = 16 * tt + m_;
      int cs = (g * 4 + q) ^ (row & 7);
      short8_t bh = *(const short8_t*)&lws[row][cs][0];
      acc[tt] = __builtin_amdgcn_mfma_f32_16x16x32_bf16(ahv[g], bh, acc[tt], 0, 0, 0);
      acc[tt] = __builtin_amdgcn_mfma_f32_16x16x32_bf16(alv[g], bh, acc[tt], 0, 0, 0);
    }
  }
  __syncthreads();

  // ---- phase St: stage lo-plane weights ----
#pragma unroll
  for (int i = 0; i < 4; i++) {
    int chi = t + 256 * i;
    int row = chi >> 4, c = chi & 15;
    short8_t wv = *(const short8_t*)&wtl[(size_t)row * 128 + c * 8];
    *(short8_t*)&lws[row][c ^ (row & 7)][0] = wv;
  }
  __syncthreads();

  // ---- phase Cb: lo-plane MFMAs ----
#pragma unroll
  for (int g = 0; g < 4; g++) {
#pragma unroll
    for (int tt = 0; tt < 4; tt++) {
      int row = 16 * tt + m_;
      int cs = (g * 4 + q) ^ (row & 7);
      short8_t bl = *(const short8_t*)&lws[row][cs][0];
      acc[tt] = __builtin_amdgcn_mfma_f32_16x16x32_bf16(ahv[g], bl, acc[tt], 0, 0, 0);
    }
  }
  // epilogue: bias + relu + hi/lo split store
#pragma unroll
  for (int tt = 0; tt < 4; tt++) {
    float bia = bias[16 * tt + m_];
#pragma unroll
    for (int reg = 0; reg < 4; reg++) {
      int node = n0b + w * 16 + q * 4 + reg;
      if (node < N) {
        float val = fmaxf(acc[tt][reg] + bia, 0.f);
        short hh = f2bf(val);
        h1h[(size_t)node * HID + 16 * tt + m_] = hh;
        h1l[(size_t)node * HID + 16 * tt + m_] = f2bf(val - bf2f(hh));
      }
    }
  }
}

// ====== layer-2: in-LDS CSR build + MERGED both-K-half register gather + phased MFMA ======
__global__ __launch_bounds__(256) void l2fused_k(
    const short* __restrict__ h1h, const short* __restrict__ h1l,
    const int* __restrict__ bcur, const unsigned* __restrict__ pk,
    const short* __restrict__ wth, const short* __restrict__ wtl,
    const float* __restrict__ bias, const float* __restrict__ linW,
    const int* __restrict__ batch, float* __restrict__ gs, float* __restrict__ gc, int N) {
  __shared__ __align__(16) short lws[64][16][8];  // 16 KB (one plane, one K-half)
  __shared__ __align__(16) int4 mid_s[192];       //  3 KB
  __shared__ int cnt_s[192];
  __shared__ unsigned ovf_s[OVCAP];               //  4 KB
  __shared__ int ovfn_s;

  const int t = threadIdx.x;
  const int lane = t & 63, w = t >> 6;
  const int m_ = lane & 15, q = lane >> 4;
  const int n0b = blockIdx.x * 64;

  // ---- phase A: hi-weights(s0) -> LDS; init build state ----
  int node_c = n0b + w * 16 + m_;
  if (node_c >= N) node_c = N - 1;
#pragma unroll
  for (int i = 0; i < 4; i++) {
    int chi = t + 256 * i;
    int row = chi >> 4, c = chi & 15;
    int g = c >> 2, qq = c & 3;
    short8_t wv = *(const short8_t*)&wth[(size_t)row * 256 + g * 64 + 0 * 32 + qq * 8];
    *(short8_t*)&lws[row][c ^ (row & 7)][0] = wv;
  }
  if (t < 192) cnt_s[t] = 0;
  if (t == 0) ovfn_s = 0;
  __syncthreads();

  // ---- phase B: in-LDS CSR build (1 LDS atomic/edge) ----
  {
    int ne = bcur[blockIdx.x * 16];
    if (ne > BCAP) ne = BCAP;
    const size_t base = (size_t)blockIdx.x * BCAP;
    for (int e = t; e < ne; e += 256) {
      unsigned p = pk[base + e];
      int srcn = (int)(p & 0x7FFFF);
      int slot = (int)((p >> 19) & 3) * 64 + (int)(p >> 21);
      int j = atomicAdd(&cnt_s[slot], 1);
      if (j < 4) ((int*)&mid_s[slot])[j] = srcn;
      else {
        int k2 = atomicAdd(&ovfn_s, 1);
        if (k2 < OVCAP) ovf_s[k2] = ((unsigned)slot << 19) | (unsigned)srcn;
      }
    }
  }
  __syncthreads();

  // ---- phase S'': merged both-K-half consumer-aligned gather -> register fragments ----
  short8_t ahv0[4], alv0[4], ahv1[4], alv1[4];
  {
    // self fragments (both halves)
    ahv0[0] = *(const short8_t*)&h1h[(size_t)node_c * HID + q * 8];
    alv0[0] = *(const short8_t*)&h1l[(size_t)node_c * HID + q * 8];
    ahv1[0] = *(const short8_t*)&h1h[(size_t)node_c * HID + 32 + q * 8];
    alv1[0] = *(const short8_t*)&h1l[(size_t)node_c * HID + 32 + q * 8];
    int ovn = ovfn_s;
    if (ovn > OVCAP) ovn = OVCAP;
    int tslot[3], tlen[3];
    int4 tid4[3];
    int gid[3][4];
#pragma unroll
    for (int k = 0; k < 3; k++) {
      tslot[k] = k * 64 + w * 16 + m_;
      tid4[k] = mid_s[tslot[k]];
      tlen[k] = cnt_s[tslot[k]];
      int nself = n0b + (tslot[k] & 63);
      if (nself >= N) nself = N - 1;
      gid[k][0] = (0 < tlen[k]) ? tid4[k].x : nself;
      gid[k][1] = (1 < tlen[k]) ? tid4[k].y : nself;
      gid[k][2] = (2 < tlen[k]) ? tid4[k].z : nself;
      gid[k][3] = (3 < tlen[k]) ? tid4[k].w : nself;
    }
    float a0[3][8], a1[3][8];
    // batch half-0: 12 independent line-opening loads
    {
      short8_t v0[3], v1[3], v2[3], v3[3];
#pragma unroll
      for (int k = 0; k < 3; k++) {
        size_t co = (size_t)q * 8;
        v0[k] = *(const short8_t*)&h1h[(size_t)gid[k][0] * HID + co];
        v1[k] = *(const short8_t*)&h1h[(size_t)gid[k][1] * HID + co];
        v2[k] = *(const short8_t*)&h1h[(size_t)gid[k][2] * HID + co];
        v3[k] = *(const short8_t*)&h1h[(size_t)gid[k][3] * HID + co];
      }
#pragma unroll
      for (int k = 0; k < 3; k++) {
        float k0 = (0 < tlen[k]) ? 1.f : 0.f;
        float k1 = (1 < tlen[k]) ? 1.f : 0.f;
        float k2 = (2 < tlen[k]) ? 1.f : 0.f;
        float k3 = (3 < tlen[k]) ? 1.f : 0.f;
#pragma unroll
        for (int i = 0; i < 8; i++)
          a0[k][i] = k0 * bf2f(v0[k][i]) + k1 * bf2f(v1[k][i]) + k2 * bf2f(v2[k][i]) +
                     k3 * bf2f(v3[k][i]);
      }
    }
    // batch half-1: same rows +64B -> L1-resident lines, no new L2/HBM fetch
    {
      short8_t v0[3], v1[3], v2[3], v3[3];
#pragma unroll
      for (int k = 0; k < 3; k++) {
        size_t co = 32 + (size_t)q * 8;
        v0[k] = *(const short8_t*)&h1h[(size_t)gid[k][0] * HID + co];
        v1[k] = *(const short8_t*)&h1h[(size_t)gid[k][1] * HID + co];
        v2[k] = *(const short8_t*)&h1h[(size_t)gid[k][2] * HID + co];
        v3[k] = *(const short8_t*)&h1h[(size_t)gid[k][3] * HID + co];
      }
#pragma unroll
      for (int k = 0; k < 3; k++) {
        float k0 = (0 < tlen[k]) ? 1.f : 0.f;
        float k1 = (1 < tlen[k]) ? 1.f : 0.f;
        float k2 = (2 < tlen[k]) ? 1.f : 0.f;
        float k3 = (3 < tlen[k]) ? 1.f : 0.f;
#pragma unroll
        for (int i = 0; i < 8; i++)
          a1[k][i] = k0 * bf2f(v0[k][i]) + k1 * bf2f(v1[k][i]) + k2 * bf2f(v2[k][i]) +
                     k3 * bf2f(v3[k][i]);
      }
    }
    // rare tail: overflow entries contribute to both halves
#pragma unroll
    for (int k = 0; k < 3; k++) {
      for (int k3_ = 0; k3_ < ovn; k3_++) {
        unsigned ov = ovf_s[k3_];
        if ((int)(ov >> 19) == tslot[k]) {
          const short* p = &h1h[(size_t)(ov & 0x7FFFF) * HID];
          short8_t u0 = *(const short8_t*)&p[q * 8];
          short8_t u1 = *(const short8_t*)&p[32 + q * 8];
#pragma unroll
          for (int i = 0; i < 8; i++) {
            a0[k][i] += bf2f(u0[i]);
            a1[k][i] += bf2f(u1[i]);
          }
        }
      }
      float inv = 1.f / fmaxf((float)tlen[k], 1.f);
#pragma unroll
      for (int i = 0; i < 8; i++) {
        a0[k][i] *= inv;
        a1[k][i] *= inv;
      }
      split8(a0[k], &ahv0[k + 1], &alv0[k + 1]);
      split8(a1[k], &ahv1[k + 1], &alv1[k + 1]);
    }
  }

  // ---- weight-phase sequence: 4 stages x MFMA, fragments from registers ----
  f32x4 acc[4];
#pragma unroll
  for (int i = 0; i < 4; i++) acc[i] = (f32x4){0.f, 0.f, 0.f, 0.f};
#pragma unroll
  for (int s_ = 0; s_ < 2; s_++) {
    if (s_ == 1) {  // re-stage hi-weights for K-half 1 (lws fully consumed; barrier passed)
#pragma unroll
      for (int i = 0; i < 4; i++) {
        int chi = t + 256 * i;
        int row = chi >> 4, c = chi & 15;
        int g = c >> 2, q2 = c & 3;
        short8_t wv = *(const short8_t*)&wth[(size_t)row * 256 + g * 64 + 32 + q2 * 8];
        *(short8_t*)&lws[row][c ^ (row & 7)][0] = wv;
      }
      __syncthreads();
    }
    // Ca(s_): hi-plane MFMAs
#pragma unroll
    for (int g = 0; g < 4; g++) {
      short8_t ah = (s_ == 0) ? ahv0[g] : ahv1[g];
      short8_t al = (s_ == 0) ? alv0[g] : alv1[g];
#pragma unroll
      for (int tt = 0; tt < 4; tt++) {
        int row = 16 * tt + m_;
        int cs = (g * 4 + q) ^ (row & 7);
        short8_t bh = *(const short8_t*)&lws[row][cs][0];
        acc[tt] = __builtin_amdgcn_mfma_f32_16x16x32_bf16(ah, bh, acc[tt], 0, 0, 0);
        acc[tt] = __builtin_amdgcn_mfma_f32_16x16x32_bf16(al, bh, acc[tt], 0, 0, 0);
      }
    }
    __syncthreads();
    // St(s_): stage lo-plane weights for this K-half
#pragma unroll
    for (int i = 0; i < 4; i++) {
      int chi = t + 256 * i;
      int row = chi >> 4, c = chi & 15;
      int g = c >> 2, q2 = c & 3;
      short8_t wv = *(const short8_t*)&wtl[(size_t)row * 256 + g * 64 + s_ * 32 + q2 * 8];
      *(short8_t*)&lws[row][c ^ (row & 7)][0] = wv;
    }
    __syncthreads();
    // Cb(s_): lo-plane MFMAs
#pragma unroll
    for (int g = 0; g < 4; g++) {
      short8_t ah = (s_ == 0) ? ahv0[g] : ahv1[g];
#pragma unroll
      for (int tt = 0; tt < 4; tt++) {
        int row = 16 * tt + m_;
        int cs = (g * 4 + q) ^ (row & 7);
        short8_t bl = *(const short8_t*)&lws[row][cs][0];
        acc[tt] = __builtin_amdgcn_mfma_f32_16x16x32_bf16(ah, bl, acc[tt], 0, 0, 0);
      }
    }
    if (s_ == 0) __syncthreads();  // protect lws before next hi-stage
  }

  // ---- pooled epilogue ----
  float bia[4], lw0[4], lw1[4];
#pragma unroll
  for (int tt = 0; tt < 4; tt++) {
    int col = 16 * tt + m_;
    bia[tt] = bias[col];
    lw0[tt] = linW[col * 2 + 0];
    lw1[tt] = linW[col * 2 + 1];
  }
#pragma unroll
  for (int reg = 0; reg < 4; reg++) {
    int node = n0b + w * 16 + q * 4 + reg;
    float p0 = 0.f, p1 = 0.f;
#pragma unroll
    for (int tt = 0; tt < 4; tt++) {
      float v = fmaxf(acc[tt][reg] + bia[tt], 0.f);
      p0 += v * lw0[tt];
      p1 += v * lw1[tt];
    }
#pragma unroll
    for (int o = 1; o < 16; o <<= 1) {
      p0 += __shfl_xor(p0, o, 64);
      p1 += __shfl_xor(p1, o, 64);
    }
    if (m_ == 0 && node < N) {
      int g = batch[node];
      atomicAdd(&gs[g * 2 + 0], p0);
      atomicAdd(&gs[g * 2 + 1], p1);
      atomicAdd(&gc[g], 1.0f);
    }
  }
}

__global__ __launch_bounds__(256) void final_k(const float* __restrict__ gs,
                                               const float* __restrict__ gc,
                                               const float* __restrict__ linb,
                                               float* __restrict__ out, int G) {
  int i = blockIdx.x * 256 + threadIdx.x;
  if (i >= G * 2) return;
  int g = i >> 1, o = i & 1;
  out[i] = gs[i] / fmaxf(gc[g], 1.0f) + linb[o];
}

extern "C" void kernel_launch(void* const* d_in, const int* in_sizes, int n_in,
                              void* d_out, int out_size, void* d_ws, size_t ws_size,
                              hipStream_t stream) {
  const int* sid = (const int*)d_in[0];
  const int* cid = (const int*)d_in[1];
  const int* pid = (const int*)d_in[2];
  const int* ei = (const int*)d_in[3];
  const int* et = (const int*)d_in[4];
  const int* batch = (const int*)d_in[5];
  const float* se = (const float*)d_in[7];
  const float* ce = (const float*)d_in[8];
  const float* pe = (const float*)d_in[9];
  const float* W1 = (const float*)d_in[10];
  const float* root1 = (const float*)d_in[11];
  const float* b1 = (const float*)d_in[12];
  const float* W2 = (const float*)d_in[13];
  const float* root2 = (const float*)d_in[14];
  const float* b2 = (const float*)d_in[15];
  const float* linW = (const float*)d_in[16];
  const float* linb = (const float*)d_in[17];
  float* out = (float*)d_out;

  const int N = in_sizes[0];
  const int E = in_sizes[4];
  const int G = out_size / 2;
  const int* src = ei;
  const int* dst = ei + E;
  const int NBk = (N + 63) / 64;     // buckets == fused-layer blocks
  const int NBa = (NBk + 15) & ~15;  // aligned allocation

  // ---- workspace layout (16B-aligned; bcur|gs|gc adjacent for one memset) ----
  char* w = (char*)d_ws;
  short* h1h = (short*)w;  w += (size_t)N * HID * sizeof(short);
  short* h1l = (short*)w;  w += (size_t)N * HID * sizeof(short);
  short* xh = (short*)w;   w += (size_t)N * EMB * sizeof(short);
  short* xl = (short*)w;   w += (size_t)N * EMB * sizeof(short);
  int* bcur = (int*)w;     w += (size_t)NBa * 16 * sizeof(int);  // 64B-padded cursors
  float* gs = (float*)w;   w += (size_t)G * 2 * sizeof(float);
  float* gc = (float*)w;   w += (size_t)G * sizeof(float);
  unsigned* pk = (unsigned*)w; w += (size_t)NBa * BCAP * sizeof(unsigned);  // 19.2 MB
  short* w1h = (short*)w;  w += (size_t)64 * 128 * sizeof(short);
  short* w1l = (short*)w;  w += (size_t)64 * 128 * sizeof(short);
  short* w2h = (short*)w;  w += (size_t)64 * 256 * sizeof(short);
  short* w2l = (short*)w;  w += (size_t)64 * 256 * sizeof(short);
  if ((size_t)(w - (char*)d_ws) > ws_size) return;  // fail loudly, no OOB

  // single memset covers bcur + gs + gc (adjacent)
  hipMemsetAsync(bcur, 0, (size_t)NBa * 16 * sizeof(int) + (size_t)G * 3 * sizeof(float),
                 stream);

  int prep_n = N * 8;  // covers E (1.5M) and weight ranges too for this problem size
  if (prep_n < E) prep_n = E;
  if (prep_n < 64 * 256) prep_n = 64 * 256;
  prep_k<<<(prep_n + 255) / 256, 256, 0, stream>>>(sid, cid, pid, se, ce, pe, xh, xl, src,
                                                   dst, et, bcur, pk, root1, W1, root2, W2,
                                                   w1h, w1l, w2h, w2l, N, E);

  l1fused_k<<<NBk, 256, 0, stream>>>(xh, xl, bcur, pk, w1h, w1l, b1, h1h, h1l, N);
  l2fused_k<<<NBk, 256, 0, stream>>>(h1h, h1l, bcur, pk, w2h, w2l, b2, linW, batch, gs, gc,
                                     N);
  final_k<<<(G * 2 + 255) / 256, 256, 0, stream>>>(gs, gc, linb, out, G);
}